// Round 5
// baseline (217.583 us; speedup 1.0000x reference)
//
#include <hip/hip_runtime.h>
#include <cstdint>

typedef __attribute__((ext_vector_type(8))) short short8;
typedef __attribute__((ext_vector_type(4))) float floatx4;

#define TWO_PI 6.283185307179586f

__device__ __forceinline__ unsigned short f2bf(float f) {
  union { float f; uint32_t u; } c; c.f = f;
  uint32_t u = c.u;
  u += 0x7FFFu + ((u >> 16) & 1u);   // RNE
  return (unsigned short)(u >> 16);
}
__device__ __forceinline__ uint32_t packbf(float re, float im) {
  return (uint32_t)f2bf(re) | ((uint32_t)f2bf(im) << 16);
}

// ---------------------------------------------------------------------------
// Four-step DFT convolution, N = 65536 = 256 x 256, t = c + 256 r, k = k1 + 256 k2.
// z_s = x[2s] + i x[2s+1].  All 256-pt DFT stages are real bf16 MFMA GEMMs via
// the 2x2 rotation embedding.  A-matrices are stored PRE-SWIZZLED in MFMA
// fragment order: chunk ((mt*KIT+it)*2+ks)*8+im holds 64 lanes x 8 shorts with
// lane(qhi,qlo) = A[mt*128+im*16+qlo][it*64+ks*32+qhi*8+j].
// ---------------------------------------------------------------------------

// value of stage matrix `which` at (row m, col k)
__device__ __forceinline__ float amat_val(int which, int m, int k) {
  const float w256 = TWO_PI / 256.0f;
  int a = m >> 1, d = m & 1, b = k >> 1, e = k & 1;
  float th = (float)((a * b) & 255) * w256;
  float sn, cs; __sincosf(th, &sn, &cs);
  if (which <= 2) {                 // E-: rows [cs, sn; -sn, cs]
    return d == 0 ? (e == 0 ? cs : sn) : (e == 0 ? -sn : cs);
  } else {                          // E+: rows [cs, -sn; sn, cs]
    return d == 0 ? (e == 0 ? cs : -sn) : (e == 0 ? sn : cs);
  }
}

// Merged prep: blocks [0,3072) build swizzled A1..A4; [3072,4096) pack x->Zp;
// [4096,4352) compute Gw[k1][c] (stage-1+twiddle of filter, fp32).
__global__ __launch_bounds__(256) void prep_all(
    const float* __restrict__ x, const float* __restrict__ filt,
    unsigned short* __restrict__ A1, unsigned short* __restrict__ A2,
    unsigned short* __restrict__ A3, unsigned short* __restrict__ A4,
    uint32_t* __restrict__ Zp, float2* __restrict__ Gw) {
  const int bid = blockIdx.x;
  const int tid = threadIdx.x;
  if (bid < 3072) {
    int idx = bid * 256 + tid;
    int which, local, KIT;
    unsigned short* dst;
    if (idx < 131072)      { which = 1; local = idx;          KIT = 4; dst = A1; }
    else if (idx < 393216) { which = 2; local = idx - 131072; KIT = 8; dst = A2; }
    else if (idx < 655360) { which = 3; local = idx - 393216; KIT = 8; dst = A3; }
    else                   { which = 4; local = idx - 655360; KIT = 8; dst = A4; }
    int j    = local & 7;
    int lane = (local >> 3) & 63;
    int qlo = lane & 15, qhi = lane >> 4;
    int im   = (local >> 9) & 7;
    int ks   = (local >> 12) & 1;
    int rest = local >> 13;
    int it = rest % KIT, mt = rest / KIT;
    int m = mt * 128 + im * 16 + qlo;
    int k = it * 64 + ks * 32 + qhi * 8 + j;
    dst[local] = f2bf(amat_val(which, m, k));
  } else if (bid < 4096) {                    // Zp[(s*256+c)][r] packed bf16 pair
    int b2 = bid - 3072;                      // (s, r-chunk of 16)
    int s = b2 >> 3, rq = b2 & 7;
    const float* x0 = x + (size_t)(2 * s) * 32768;
    const float* x1 = x0 + 32768;
    uint32_t v[16];
    #pragma unroll
    for (int rr = 0; rr < 16; ++rr) {
      int t = tid + 256 * (rq * 16 + rr);
      v[rr] = (uint32_t)f2bf(x0[t]) | ((uint32_t)f2bf(x1[t]) << 16);
    }
    uint32_t* dst = Zp + (size_t)(s * 256 + tid) * 128 + rq * 16;
    #pragma unroll
    for (int j = 0; j < 16; j += 4)
      *(uint4*)(dst + j) = make_uint4(v[j], v[j + 1], v[j + 2], v[j + 3]);
  } else {                                    // Gw[k1][c], fp32
    int k1 = bid - 4096, c = tid;
    float ar = 0.f, ai = 0.f;
    for (int r = 0; r < 128; ++r) {
      float v = filt[c + 256 * r];
      float th = (float)((k1 * r) & 255) * (TWO_PI / 256.0f);
      float sn, cs; __sincosf(th, &sn, &cs);
      ar += v * cs; ai -= v * sn;
    }
    float th = (float)((k1 * c) & 65535) * (TWO_PI / 65536.0f);
    float sn, cs; __sincosf(th, &sn, &cs);
    Gw[(k1 << 8) + c] = make_float2(ar * cs + ai * sn, ai * cs - ar * sn);
  }
}

// WtT[k2][k1] = sum_c Gw[k1][c] E-(k2 c/256)   (fp32, transposed for coalesced use)
__global__ __launch_bounds__(256) void prep_wb(const float2* __restrict__ Gw,
                                               float2* __restrict__ WtT) {
  int k1 = blockIdx.x, k2 = threadIdx.x;
  float ar = 0.f, ai = 0.f;
  for (int c = 0; c < 256; ++c) {
    float2 g = Gw[(k1 << 8) + c];
    float th = (float)((k2 * c) & 255) * (TWO_PI / 256.0f);
    float sn, cs; __sincosf(th, &sn, &cs);
    ar += g.x * cs + g.y * sn;
    ai += g.y * cs - g.x * sn;
  }
  WtT[(k2 << 8) + k1] = make_float2(ar, ai);
}

// One DFT stage: C[128m x 256n] tile per block, A-frags direct from the
// swizzled table (global/L2), B staged via dbuf global_load_lds (32KB x2).
// MODE 1: *E-(k1 c/65536) -> G2[(s,k1)][c].  MODE 2: *WtT -> P[(s,k1)][k2] (LDS transpose).
// MODE 3: *E+(k1 c/65536) -> H2[(s,c)][k1].  MODE 4: write y (scale 1/65536).
template <int MODE, int KITERS>
__global__ __launch_bounds__(256, 2) void dft_stage(
    const unsigned short* __restrict__ Af,
    const unsigned short* __restrict__ Bd,
    uint32_t* __restrict__ outp,
    float* __restrict__ yout,
    const float2* __restrict__ WtT) {
  __shared__ unsigned short Sm[34816];        // 69632 B: B0|B1 (32KB each); MODE2 Tr reuse
  constexpr int KP = KITERS * 64;

  const int nt = blockIdx.x & 127;            // = s
  const int mt = blockIdx.x >> 7;
  const int n0 = nt * 256;

  const int tid = threadIdx.x;
  const int w = tid >> 6, lane = tid & 63;
  const int qlo = lane & 15, qhi = lane >> 4;
  const int r8 = lane >> 3, pl = lane & 7, sj = pl ^ r8, q3 = qlo & 7;

  floatx4 acc[8][4];
  #pragma unroll
  for (int i = 0; i < 8; ++i)
    #pragma unroll
    for (int j = 0; j < 4; ++j) acc[i][j] = (floatx4){0.f, 0.f, 0.f, 0.f};

  auto issueB = [&](int it, int buf) {
    const int k0 = it * 64;
    unsigned short* Bsb = Sm + buf * 16384;
    #pragma unroll
    for (int q = 0; q < 8; ++q) {
      const int R = w * 64 + q * 8 + r8;
      const unsigned short* gB = Bd + (size_t)(n0 + R) * KP + k0 + sj * 8;
      __builtin_amdgcn_global_load_lds(
          (const __attribute__((address_space(1))) uint32_t*)gB,
          (__attribute__((address_space(3))) uint32_t*)&Bsb[(w * 64 + q * 8) * 64], 16, 0, 0);
    }
  };

  issueB(0, 0);
  for (int it = 0; it < KITERS; ++it) {
    __syncthreads();                          // drains staging for buf it&1
    if (it + 1 < KITERS) issueB(it + 1, (it + 1) & 1);
    const unsigned short* Bb = Sm + (it & 1) * 16384;
    const unsigned short* Ab = Af + (size_t)((mt * KITERS + it) * 2) * 8 * 512;
    #pragma unroll
    for (int ks = 0; ks < 2; ++ks) {
      short8 a[8], bb[4];
      #pragma unroll
      for (int im = 0; im < 8; ++im)
        a[im] = *(const short8*)(Ab + ((ks * 8 + im) << 9) + (lane << 3));
      #pragma unroll
      for (int in = 0; in < 4; ++in)
        bb[in] = *(const short8*)&Bb[(w * 64 + in * 16 + qlo) * 64 + (((ks * 4 + qhi) ^ q3) << 3)];
      #pragma unroll
      for (int im = 0; im < 8; ++im)
        #pragma unroll
        for (int in = 0; in < 4; ++in)
          acc[im][in] = __builtin_amdgcn_mfma_f32_16x16x32_bf16(a[im], bb[in], acc[im][in], 0, 0, 0);
    }
  }

  if (MODE == 2) {
    __syncthreads();                          // staging dead -> reuse as Tr[256][68] u32
    uint32_t* Tr = (uint32_t*)Sm;
    #pragma unroll
    for (int im = 0; im < 8; ++im) {
      #pragma unroll
      for (int in = 0; in < 4; ++in) {
        const int nloc = w * 64 + in * 16 + qlo;
        #pragma unroll
        for (int pp = 0; pp < 2; ++pp) {
          const int mloc = im * 8 + qhi * 2 + pp;
          const int mC = mt * 64 + mloc;               // global k2
          float re = acc[im][in][2 * pp], iv = acc[im][in][2 * pp + 1];
          float2 wv = WtT[(mC << 8) + nloc];           // coalesced (lanes -> k1)
          float r2 = re * wv.x - iv * wv.y, i2 = re * wv.y + iv * wv.x;
          Tr[nloc * 68 + mloc] = packbf(r2, i2);
        }
      }
    }
    __syncthreads();
    uint32_t* dst = outp + (size_t)((nt << 8) + tid) * 256 + mt * 64;
    const uint32_t* srcp = Tr + tid * 68;
    #pragma unroll
    for (int j = 0; j < 64; j += 4)
      *(uint4*)(dst + j) = *(const uint4*)(srcp + j);
    return;
  }

  #pragma unroll
  for (int im = 0; im < 8; ++im) {
    #pragma unroll
    for (int in = 0; in < 4; ++in) {
      const int nloc = w * 64 + in * 16 + qlo;
      #pragma unroll
      for (int pp = 0; pp < 2; ++pp) {
        const int mC = mt * 64 + im * 8 + qhi * 2 + pp;
        float re = acc[im][in][2 * pp], iv = acc[im][in][2 * pp + 1];
        if (MODE == 1) {
          float th = (float)((mC * nloc) & 65535) * (TWO_PI / 65536.0f);
          float sn, cs; __sincosf(th, &sn, &cs);       // E-
          float r2 = re * cs + iv * sn, i2 = iv * cs - re * sn;
          outp[(size_t)((nt << 8) + mC) * 256 + nloc] = packbf(r2, i2);
        } else if (MODE == 3) {
          float th = (float)((mC * nloc) & 65535) * (TWO_PI / 65536.0f);
          float sn, cs; __sincosf(th, &sn, &cs);       // E+
          float r2 = re * cs - iv * sn, i2 = iv * cs + re * sn;
          outp[(size_t)((nt << 8) + mC) * 256 + nloc] = packbf(r2, i2);
        } else {                                       // MODE 4: final y
          const float sc = 1.0f / 65536.0f;
          float* y0 = yout + ((size_t)nt << 16) + (mC << 8) + nloc;
          y0[0] = re * sc;        // y[2s][c+256r]
          y0[32768] = iv * sc;    // y[2s+1][c+256r]
        }
      }
    }
  }
}

extern "C" void kernel_launch(void* const* d_in, const int* in_sizes, int n_in,
                              void* d_out, int out_size, void* d_ws, size_t ws_size,
                              hipStream_t stream) {
  const float* x = (const float*)d_in[0];     // [256][32768] fp32
  const float* filt = (const float*)d_in[1];  // [1][32768] fp32
  float* Y = (float*)d_out;                   // [256][32768] fp32

  char* ws = (char*)d_ws;
  unsigned short* A1 = (unsigned short*)(ws + 0);              // 256 KB
  unsigned short* A2 = (unsigned short*)(ws + 0x40000);        // 512 KB
  unsigned short* A3 = (unsigned short*)(ws + 0xC0000);        // 512 KB
  unsigned short* A4 = (unsigned short*)(ws + 0x140000);       // 256 KB
  float2* Gw  = (float2*)(ws + 0x180000);                      // 512 KB
  float2* WtT = (float2*)(ws + 0x200000);                      // 512 KB
  unsigned short* Zp = (unsigned short*)(ws + (3u << 20));     // 16 MB  [3,19)
  unsigned short* G2 = (unsigned short*)(ws + 19922944u);      // 32 MB  [19,51)
  unsigned short* P  = (unsigned short*)(ws + 53477376u);      // 32 MB  [51,83)
  unsigned short* H2 = (unsigned short*)(ws + (3u << 20));     // 32 MB, reuses Zp+G2 (dead)

  hipLaunchKernelGGL(prep_all, dim3(4352), dim3(256), 0, stream,
                     x, filt, A1, A2, A3, A4, (uint32_t*)Zp, Gw);
  hipLaunchKernelGGL(prep_wb, dim3(256), dim3(256), 0, stream, Gw, WtT);

  hipLaunchKernelGGL((dft_stage<1, 4>), dim3(512), dim3(256), 0, stream,
                     A1, Zp, (uint32_t*)G2, (float*)nullptr, (const float2*)nullptr);
  hipLaunchKernelGGL((dft_stage<2, 8>), dim3(512), dim3(256), 0, stream,
                     A2, G2, (uint32_t*)P, (float*)nullptr, WtT);
  hipLaunchKernelGGL((dft_stage<3, 8>), dim3(512), dim3(256), 0, stream,
                     A3, P, (uint32_t*)H2, (float*)nullptr, (const float2*)nullptr);
  hipLaunchKernelGGL((dft_stage<4, 8>), dim3(256), dim3(256), 0, stream,
                     A4, H2, (uint32_t*)nullptr, Y, (const float2*)nullptr);
}

// Round 6
// 214.649 us; speedup vs baseline: 1.0137x; 1.0137x over previous
//
#include <hip/hip_runtime.h>
#include <cstdint>

typedef __attribute__((ext_vector_type(8))) short short8;
typedef __attribute__((ext_vector_type(4))) float floatx4;

#define TWO_PI 6.283185307179586f

__device__ __forceinline__ unsigned short f2bf(float f) {
  union { float f; uint32_t u; } c; c.f = f;
  uint32_t u = c.u;
  u += 0x7FFFu + ((u >> 16) & 1u);   // RNE
  return (unsigned short)(u >> 16);
}
__device__ __forceinline__ uint32_t packbf(float re, float im) {
  return (uint32_t)f2bf(re) | ((uint32_t)f2bf(im) << 16);
}

// ---------------------------------------------------------------------------
// Four-step DFT convolution, N = 65536 = 256 x 256, t = c + 256 r, k = k1 + 256 k2.
// z_s = x[2s] + i x[2s+1].  All 256-pt DFT stages are real bf16 MFMA GEMMs via
// the 2x2 rotation embedding.  A-matrices stored PRE-SWIZZLED in MFMA fragment
// order: chunk ((mt*KIT+it)*2+ks)*8+im holds 64 lanes x 8 shorts with
// lane(qhi,qlo) = A[mt*128+im*16+qlo][it*64+ks*32+qhi*8+j].
// ---------------------------------------------------------------------------

__device__ __forceinline__ float amat_val(int which, int m, int k) {
  const float w256 = TWO_PI / 256.0f;
  int a = m >> 1, d = m & 1, b = k >> 1, e = k & 1;
  float th = (float)((a * b) & 255) * w256;
  float sn, cs; __sincosf(th, &sn, &cs);
  if (which <= 2) {                 // E-: rows [cs, sn; -sn, cs]
    return d == 0 ? (e == 0 ? cs : sn) : (e == 0 ? -sn : cs);
  } else {                          // E+: rows [cs, -sn; sn, cs]
    return d == 0 ? (e == 0 ? cs : -sn) : (e == 0 ? sn : cs);
  }
}

// Merged prep: blocks [0,3072) build swizzled A1..A4; [3072,4096) pack x->Zp;
// [4096,4352) compute Gw[k1][c] (stage-1+twiddle of filter, fp32).
__global__ __launch_bounds__(256) void prep_all(
    const float* __restrict__ x, const float* __restrict__ filt,
    unsigned short* __restrict__ A1, unsigned short* __restrict__ A2,
    unsigned short* __restrict__ A3, unsigned short* __restrict__ A4,
    uint32_t* __restrict__ Zp, float2* __restrict__ Gw) {
  const int bid = blockIdx.x;
  const int tid = threadIdx.x;
  if (bid < 3072) {
    int idx = bid * 256 + tid;
    int which, local, KIT;
    unsigned short* dst;
    if (idx < 131072)      { which = 1; local = idx;          KIT = 4; dst = A1; }
    else if (idx < 393216) { which = 2; local = idx - 131072; KIT = 8; dst = A2; }
    else if (idx < 655360) { which = 3; local = idx - 393216; KIT = 8; dst = A3; }
    else                   { which = 4; local = idx - 655360; KIT = 8; dst = A4; }
    int j    = local & 7;
    int lane = (local >> 3) & 63;
    int qlo = lane & 15, qhi = lane >> 4;
    int im   = (local >> 9) & 7;
    int ks   = (local >> 12) & 1;
    int rest = local >> 13;
    int it = rest % KIT, mt = rest / KIT;
    int m = mt * 128 + im * 16 + qlo;
    int k = it * 64 + ks * 32 + qhi * 8 + j;
    dst[local] = f2bf(amat_val(which, m, k));
  } else if (bid < 4096) {                    // Zp[(s*256+c)][r] packed bf16 pair
    int b2 = bid - 3072;                      // (s, r-chunk of 16)
    int s = b2 >> 3, rq = b2 & 7;
    const float* x0 = x + (size_t)(2 * s) * 32768;
    const float* x1 = x0 + 32768;
    uint32_t v[16];
    #pragma unroll
    for (int rr = 0; rr < 16; ++rr) {
      int t = tid + 256 * (rq * 16 + rr);
      v[rr] = (uint32_t)f2bf(x0[t]) | ((uint32_t)f2bf(x1[t]) << 16);
    }
    uint32_t* dst = Zp + (size_t)(s * 256 + tid) * 128 + rq * 16;
    #pragma unroll
    for (int j = 0; j < 16; j += 4)
      *(uint4*)(dst + j) = make_uint4(v[j], v[j + 1], v[j + 2], v[j + 3]);
  } else {                                    // Gw[k1][c], fp32
    int k1 = bid - 4096, c = tid;
    float ar = 0.f, ai = 0.f;
    for (int r = 0; r < 128; ++r) {
      float v = filt[c + 256 * r];
      float th = (float)((k1 * r) & 255) * (TWO_PI / 256.0f);
      float sn, cs; __sincosf(th, &sn, &cs);
      ar += v * cs; ai -= v * sn;
    }
    float th = (float)((k1 * c) & 65535) * (TWO_PI / 65536.0f);
    float sn, cs; __sincosf(th, &sn, &cs);
    Gw[(k1 << 8) + c] = make_float2(ar * cs + ai * sn, ai * cs - ar * sn);
  }
}

// WtT[k2][k1] = sum_c Gw[k1][c] E-(k2 c/256)   (fp32, transposed for coalesced use)
__global__ __launch_bounds__(256) void prep_wb(const float2* __restrict__ Gw,
                                               float2* __restrict__ WtT) {
  int k1 = blockIdx.x, k2 = threadIdx.x;
  float ar = 0.f, ai = 0.f;
  for (int c = 0; c < 256; ++c) {
    float2 g = Gw[(k1 << 8) + c];
    float th = (float)((k2 * c) & 255) * (TWO_PI / 256.0f);
    float sn, cs; __sincosf(th, &sn, &cs);
    ar += g.x * cs + g.y * sn;
    ai += g.y * cs - g.x * sn;
  }
  WtT[(k2 << 8) + k1] = make_float2(ar, ai);
}

// One DFT stage: C[128m x 128n] per block. A-frags direct from swizzled table
// (L2-resident), B staged via dbuf global_load_lds (16KB x2). All 16 A-loads
// of an iteration are issued BEFORE the next-iter B staging so A-waits are
// vmcnt(16)/vmcnt(8) and never drain the B prefetch.
// MODE 1: *E-(k1 c/65536) -> G2[(s,k1)][c].  MODE 2: *WtT -> P[(s,k1)][k2] (LDS transpose).
// MODE 3: *E+(k1 c/65536) -> H2[(s,c)][k1].  MODE 4: write y (scale 1/65536).
template <int MODE, int KITERS>
__global__ __launch_bounds__(256, 3) void dft_stage(
    const unsigned short* __restrict__ Af,
    const unsigned short* __restrict__ Bd,
    uint32_t* __restrict__ outp,
    float* __restrict__ yout,
    const float2* __restrict__ WtT) {
  __shared__ unsigned short Sm[16384];        // 32 KB: B0|B1 (16 KB each); MODE2 Tr reuse
  constexpr int KP = KITERS * 64;

  const int nt = blockIdx.x & 255;
  const int mt = blockIdx.x >> 8;
  const int n0 = nt * 128;
  const int s_idx = nt >> 1;
  const int cl0 = (nt & 1) * 128;

  const int tid = threadIdx.x;
  const int w = tid >> 6, lane = tid & 63;
  const int qlo = lane & 15, qhi = lane >> 4;
  const int r8 = lane >> 3, pl = lane & 7, sj = pl ^ r8, q3 = qlo & 7;

  floatx4 acc[8][2];
  #pragma unroll
  for (int i = 0; i < 8; ++i)
    #pragma unroll
    for (int j = 0; j < 2; ++j) acc[i][j] = (floatx4){0.f, 0.f, 0.f, 0.f};

  auto issueB = [&](int it, int buf) {
    const int k0 = it * 64;
    unsigned short* Bsb = Sm + buf * 8192;
    #pragma unroll
    for (int q = 0; q < 4; ++q) {
      const int R = w * 32 + q * 8 + r8;
      const unsigned short* gB = Bd + (size_t)(n0 + R) * KP + k0 + sj * 8;
      __builtin_amdgcn_global_load_lds(
          (const __attribute__((address_space(1))) uint32_t*)gB,
          (__attribute__((address_space(3))) uint32_t*)&Bsb[(w * 32 + q * 8) * 64], 16, 0, 0);
    }
  };

  issueB(0, 0);
  #pragma unroll 1
  for (int it = 0; it < KITERS; ++it) {
    __syncthreads();                          // drains staging for buf it&1 (and A)
    // ALL 16 A-fragment loads first (oldest in vmcnt queue)
    const unsigned short* Ab = Af + (size_t)((mt * KITERS + it) * 2) * 8 * 512;
    short8 a0[8], a1[8];
    #pragma unroll
    for (int im = 0; im < 8; ++im)
      a0[im] = *(const short8*)(Ab + (im << 9) + (lane << 3));
    #pragma unroll
    for (int im = 0; im < 8; ++im)
      a1[im] = *(const short8*)(Ab + ((8 + im) << 9) + (lane << 3));
    // THEN prefetch next B tile (newest; never drained by A-waits)
    if (it + 1 < KITERS) issueB(it + 1, (it + 1) & 1);

    const unsigned short* Bb = Sm + (it & 1) * 8192;
    #pragma unroll
    for (int ks = 0; ks < 2; ++ks) {
      short8 bb[2];
      #pragma unroll
      for (int in = 0; in < 2; ++in)
        bb[in] = *(const short8*)&Bb[(w * 32 + in * 16 + qlo) * 64 + (((ks * 4 + qhi) ^ q3) << 3)];
      #pragma unroll
      for (int im = 0; im < 8; ++im)
        #pragma unroll
        for (int in = 0; in < 2; ++in)
          acc[im][in] = __builtin_amdgcn_mfma_f32_16x16x32_bf16(
              ks == 0 ? a0[im] : a1[im], bb[in], acc[im][in], 0, 0, 0);
    }
  }

  if (MODE == 2) {
    __syncthreads();                          // staging dead -> Tr[128][64] u32, XOR swizzle
    uint32_t* Tr = (uint32_t*)Sm;
    #pragma unroll
    for (int im = 0; im < 8; ++im) {
      #pragma unroll
      for (int in = 0; in < 2; ++in) {
        const int nloc = w * 32 + in * 16 + qlo;
        #pragma unroll
        for (int pp = 0; pp < 2; ++pp) {
          const int mloc = im * 8 + qhi * 2 + pp;
          const int mC = mt * 64 + mloc;               // global k2
          float re = acc[im][in][2 * pp], iv = acc[im][in][2 * pp + 1];
          float2 wv = WtT[(mC << 8) + cl0 + nloc];     // coalesced (lanes -> k1)
          float r2 = re * wv.x - iv * wv.y, i2 = re * wv.y + iv * wv.x;
          Tr[nloc * 64 + (mloc ^ ((nloc & 7) << 2))] = packbf(r2, i2);
        }
      }
    }
    __syncthreads();
    const int ln = tid >> 1, half = tid & 1;
    const int xorv = (ln & 7) << 2;
    uint32_t* dst = outp + (size_t)((s_idx << 8) + cl0 + ln) * 256 + mt * 64 + half * 32;
    #pragma unroll
    for (int j = 0; j < 32; j += 4) {
      uint4 v = *(const uint4*)(Tr + ln * 64 + ((half * 32 + j) ^ xorv));
      *(uint4*)(dst + j) = v;
    }
    return;
  }

  #pragma unroll
  for (int im = 0; im < 8; ++im) {
    #pragma unroll
    for (int in = 0; in < 2; ++in) {
      const int nloc = w * 32 + in * 16 + qlo;
      const int cloc = cl0 + nloc;
      #pragma unroll
      for (int pp = 0; pp < 2; ++pp) {
        const int mC = mt * 64 + im * 8 + qhi * 2 + pp;
        float re = acc[im][in][2 * pp], iv = acc[im][in][2 * pp + 1];
        if (MODE == 1) {
          float th = (float)((mC * cloc) & 65535) * (TWO_PI / 65536.0f);
          float sn, cs; __sincosf(th, &sn, &cs);       // E-
          float r2 = re * cs + iv * sn, i2 = iv * cs - re * sn;
          outp[(size_t)((s_idx << 8) + mC) * 256 + cloc] = packbf(r2, i2);
        } else if (MODE == 3) {
          float th = (float)((mC * cloc) & 65535) * (TWO_PI / 65536.0f);
          float sn, cs; __sincosf(th, &sn, &cs);       // E+
          float r2 = re * cs - iv * sn, i2 = iv * cs + re * sn;
          outp[(size_t)((s_idx << 8) + mC) * 256 + cloc] = packbf(r2, i2);
        } else {                                       // MODE 4: final y
          const float sc = 1.0f / 65536.0f;
          float* y0 = yout + ((size_t)s_idx << 16) + (mC << 8) + cloc;
          y0[0] = re * sc;        // y[2s][c+256r]
          y0[32768] = iv * sc;    // y[2s+1][c+256r]
        }
      }
    }
  }
}

extern "C" void kernel_launch(void* const* d_in, const int* in_sizes, int n_in,
                              void* d_out, int out_size, void* d_ws, size_t ws_size,
                              hipStream_t stream) {
  const float* x = (const float*)d_in[0];     // [256][32768] fp32
  const float* filt = (const float*)d_in[1];  // [1][32768] fp32
  float* Y = (float*)d_out;                   // [256][32768] fp32

  char* ws = (char*)d_ws;
  unsigned short* A1 = (unsigned short*)(ws + 0);              // 256 KB
  unsigned short* A2 = (unsigned short*)(ws + 0x40000);        // 512 KB
  unsigned short* A3 = (unsigned short*)(ws + 0xC0000);        // 512 KB
  unsigned short* A4 = (unsigned short*)(ws + 0x140000);       // 256 KB
  float2* Gw  = (float2*)(ws + 0x180000);                      // 512 KB
  float2* WtT = (float2*)(ws + 0x200000);                      // 512 KB
  unsigned short* Zp = (unsigned short*)(ws + (3u << 20));     // 16 MB  [3,19)
  unsigned short* G2 = (unsigned short*)(ws + 19922944u);      // 32 MB  [19,51)
  unsigned short* P  = (unsigned short*)(ws + 53477376u);      // 32 MB  [51,83)
  unsigned short* H2 = (unsigned short*)(ws + (3u << 20));     // 32 MB, reuses Zp+G2 (dead)

  hipLaunchKernelGGL(prep_all, dim3(4352), dim3(256), 0, stream,
                     x, filt, A1, A2, A3, A4, (uint32_t*)Zp, Gw);
  hipLaunchKernelGGL(prep_wb, dim3(256), dim3(256), 0, stream, Gw, WtT);

  hipLaunchKernelGGL((dft_stage<1, 4>), dim3(1024), dim3(256), 0, stream,
                     A1, Zp, (uint32_t*)G2, (float*)nullptr, (const float2*)nullptr);
  hipLaunchKernelGGL((dft_stage<2, 8>), dim3(1024), dim3(256), 0, stream,
                     A2, G2, (uint32_t*)P, (float*)nullptr, WtT);
  hipLaunchKernelGGL((dft_stage<3, 8>), dim3(1024), dim3(256), 0, stream,
                     A3, P, (uint32_t*)H2, (float*)nullptr, (const float2*)nullptr);
  hipLaunchKernelGGL((dft_stage<4, 8>), dim3(512), dim3(256), 0, stream,
                     A4, H2, (uint32_t*)nullptr, Y, (const float2*)nullptr);
}